// Round 10
// baseline (232.382 us; speedup 1.0000x reference)
//
#include <hip/hip_runtime.h>
#include <hip/hip_bf16.h>

// Problem: B=2, LQ=2048, LK=4096, D_MODEL=512, NHEAD=8, D_HEAD=64
// Inputs fp32 (+ int32 mask). Internal: bf16 MFMA, fp32 accumulation.
// Round 10:
//  - attn: async double-buffered K/V staging (global_load_lds, 2-deep
//    pipeline, 1 barrier/iter) with XOR-swizzled LDS layout (DMA forces
//    lane-contiguous writes; swizzle keeps b128 reads bank-balanced).
//  - proj: W-phases 2x256 -> 4x128 (LDS 33->17.4 KB) => 8 blocks/CU.

using bf16  = __hip_bfloat16;
using bf16x8 = __attribute__((ext_vector_type(8))) short;  // 8 bf16 = 4 VGPRs
using f32x4  = __attribute__((ext_vector_type(4))) float;

#define MFMA16(a, b, c) __builtin_amdgcn_mfma_f32_16x16x32_bf16((a), (b), (c), 0, 0, 0)

// 0.125 * log2(e): folds the 1/sqrt(64) scale and the exp->exp2 conversion
#define SCALE_LOG2E 0.18033688011112042f

__device__ __forceinline__ bf16x8 load8(const bf16* p) {
    return *reinterpret_cast<const bf16x8*>(p);
}
__device__ __forceinline__ short f2bf(float x) {
    bf16 h = __float2bfloat16(x);
    return *reinterpret_cast<short*>(&h);
}
__device__ __forceinline__ short f2bf_fast(float x) {   // round-half-up
    unsigned u = (__builtin_bit_cast(unsigned, x) + 0x8000u) >> 16;
    return (short)u;
}
__device__ __forceinline__ float bfb2f(short s) {
    unsigned int u = ((unsigned int)(unsigned short)s) << 16;
    return __builtin_bit_cast(float, u);
}

// async global->LDS DMA: LDS dest = wave-uniform base + lane*size
__device__ __forceinline__ void async16(const bf16* g, bf16* l) {
    __builtin_amdgcn_global_load_lds(
        (const __attribute__((address_space(1))) void*)g,
        (__attribute__((address_space(3))) void*)l, 16, 0, 0);
}
__device__ __forceinline__ void async4(const float* g, float* l) {
    __builtin_amdgcn_global_load_lds(
        (const __attribute__((address_space(1))) void*)g,
        (__attribute__((address_space(3))) void*)l, 4, 0, 0);
}

// ---------------------------------------------------------------------------
// One fused prep launch, 7200 blocks (cvt q/kv, cvt weights, gate->log2)
// ---------------------------------------------------------------------------
__global__ void prep_all(const float* __restrict__ q, const float* __restrict__ kv,
                         const float* __restrict__ Wq, const float* __restrict__ Wk,
                         const float* __restrict__ Wv, const float* __restrict__ Wo,
                         const float* __restrict__ gate, const int* __restrict__ mask,
                         bf16* __restrict__ qb, bf16* __restrict__ kvb,
                         bf16* __restrict__ Wqb, bf16* __restrict__ Wkb,
                         bf16* __restrict__ Wvb, bf16* __restrict__ Wob,
                         float* __restrict__ g2) {
    const int bid = blockIdx.x;
    const int tid = threadIdx.x;
    if (bid < 7168) {
        const float* src; bf16* dst; int j;
        if (bid < 6144) {
            int i = bid * 256 + tid;                  // 0..1572863
            if (i < 524288) { src = q;  dst = qb;  j = i; }
            else            { src = kv; dst = kvb; j = i - 524288; }
        } else {
            int i = (bid - 6144) * 256 + tid;         // 0..262143
            int t = i >> 16; j = i & 65535;
            src = (t == 0) ? Wq : (t == 1) ? Wk : (t == 2) ? Wv : Wo;
            dst = (t == 0) ? Wqb : (t == 1) ? Wkb : (t == 2) ? Wvb : Wob;
        }
        float4 v = reinterpret_cast<const float4*>(src)[j];
        ushort4 o;
        o.x = (unsigned short)f2bf(v.x);
        o.y = (unsigned short)f2bf(v.y);
        o.z = (unsigned short)f2bf(v.z);
        o.w = (unsigned short)f2bf(v.w);
        reinterpret_cast<ushort4*>(dst)[j] = o;
    } else {
        int i = (bid - 7168) * 256 + tid;             // 0..8191
        float gv = fmaxf(gate[i], 1e-6f);
        g2[i] = mask[i] ? log2f(gv) : -1e30f;
    }
}

// ---------------------------------------------------------------------------
// Projection body: C = X @ W^T + bias. X:[M,512] bf16, W bf16 row-major.
// Block 256 thr / 4 waves; tile 128 rows x 64 cols; wave 32x64.
// W col-block in LDS, FOUR 128-wide K phases (Ws 17.4 KB -> 8 blocks/CU;
// 32 waves/CU hides the global A-gather latency).
// ---------------------------------------------------------------------------
__device__ __forceinline__ void proj_body(const bf16* __restrict__ X,
                                          const bf16* __restrict__ W,
                                          const float* __restrict__ bias,
                                          void* __restrict__ Cout,
                                          int mode, int L, int mb, bf16* Ws) {
    const int tid  = threadIdx.x;
    const int wave = tid >> 6;
    const int lane = tid & 63;
    const int li   = lane & 15;
    const int quad = lane >> 4;
    const int n0   = blockIdx.x * 64;
    const int m0   = mb * 128 + wave * 32;

    f32x4 zero = {0.f, 0.f, 0.f, 0.f};
    f32x4 acc[2][4];
    for (int mt = 0; mt < 2; ++mt)
        for (int t = 0; t < 4; ++t) acc[mt][t] = zero;

    const bf16* x0 = X + (size_t)(m0 + li) * 512;
    const bf16* x1 = X + (size_t)(m0 + 16 + li) * 512;

    for (int p = 0; p < 4; ++p) {
        __syncthreads();
        // stage W[n0..n0+63][p*128..p*128+127]: 1024 slots of 16B, 4/thread
        for (int i = 0; i < 4; ++i) {
            const int slot = i * 256 + tid;
            const int row  = slot >> 4;
            const int g    = slot & 15;
            *reinterpret_cast<bf16x8*>(&Ws[row * 136 + g * 8]) =
                load8(W + (size_t)(n0 + row) * 512 + p * 128 + g * 8);
        }
        __syncthreads();

        for (int k0 = 0; k0 < 128; k0 += 32) {
            bf16x8 a0 = load8(x0 + p * 128 + k0 + quad * 8);
            bf16x8 a1 = load8(x1 + p * 128 + k0 + quad * 8);
            for (int t = 0; t < 4; ++t) {
                bf16x8 w8 = load8(&Ws[(t * 16 + li) * 136 + k0 + quad * 8]);
                acc[0][t] = MFMA16(a0, w8, acc[0][t]);
                acc[1][t] = MFMA16(a1, w8, acc[1][t]);
            }
        }
    }

    for (int t = 0; t < 4; ++t) {
        const int col = n0 + t * 16 + li;
        const float bcol = bias[col];
        for (int mt = 0; mt < 2; ++mt) {
            for (int r = 0; r < 4; ++r) {
                const int row = m0 + mt * 16 + quad * 4 + r;   // C-layout
                const float v = acc[mt][t][r] + bcol;
                if (mode == 0) {
                    ((float*)Cout)[(size_t)row * 512 + col] = v;
                } else {
                    const int bb2 = row / L;
                    const int i   = row - bb2 * L;
                    const int hh  = col >> 6;
                    const int dh  = col & 63;
                    size_t idx;
                    if (mode == 1) idx = ((size_t)(bb2 * 8 + hh) * L + i) * 64 + dh;
                    else           idx = ((size_t)(bb2 * 8 + hh) * 64 + dh) * L + i;
                    ((bf16*)Cout)[idx] = __float2bfloat16(v);
                }
            }
        }
    }
}

// Fused Q/K/V projections: grid (8, 160). y<32: Q; y<96: K; else V.
__global__ void __launch_bounds__(256, 8)
proj_qkv(const bf16* __restrict__ qb, const bf16* __restrict__ kvb,
         const bf16* __restrict__ Wq, const float* __restrict__ bq,
         const bf16* __restrict__ Wk, const float* __restrict__ bk,
         const bf16* __restrict__ Wv, const float* __restrict__ bv,
         bf16* __restrict__ qp, bf16* __restrict__ kp,
         bf16* __restrict__ vpt) {
    __shared__ alignas(16) bf16 Ws[64 * 136];
    const int my = blockIdx.y;
    if (my < 32)      proj_body(qb,  Wq, bq, qp,  1, 2048, my,      Ws);
    else if (my < 96) proj_body(kvb, Wk, bk, kp,  1, 4096, my - 32, Ws);
    else              proj_body(kvb, Wv, bv, vpt, 2, 4096, my - 96, Ws);
}

// Output projection: grid (8, 32), fp32 out.
__global__ void __launch_bounds__(256, 8)
proj_o(const bf16* __restrict__ op, const bf16* __restrict__ Wo,
       const float* __restrict__ bo, float* __restrict__ out) {
    __shared__ alignas(16) bf16 Ws[64 * 136];
    proj_body(op, Wo, bo, out, 0, 1, blockIdx.y, Ws);
}

// ---------------------------------------------------------------------------
// K-split flash attention with async double-buffered K/V staging.
// Grid: 1024 = b(2) x h(8) x qtile(16) x ks(4); 256 thr = 4 waves,
// wave owns 32 Q-rows. XOR-swizzled K/V LDS layout:
//   slot(r, c) = r*8 + (c ^ (r&7)); DMA lane j of chunk (wave,half) loads
//   global (r = wave*16 + half*8 + (j>>3), c = (j&7) ^ (j>>3)) so the forced
//   lane-contiguous LDS write lands each 16B group at its swizzled slot.
// Fragment read for row R, group g: offset R*64 + ((g ^ (R&7))*8) -> 8 lanes
// per 4-bank group = ideal b128 balance. One barrier per iteration: it
// drains vmcnt -> tile i's DMA (issued during iter i-1's compute) is ready.
// ---------------------------------------------------------------------------
#define PTS 68   // P tile stride (padded; VALU-written)
__global__ void attn_kernel(const bf16* __restrict__ qp, const bf16* __restrict__ kp,
                            const bf16* __restrict__ vpt, const float* __restrict__ g2,
                            bf16* __restrict__ Opart, float* __restrict__ lpart) {
    __shared__ alignas(16) bf16 Kt[2][64 * 64];
    __shared__ alignas(16) bf16 Vt[2][64 * 64];
    __shared__ alignas(16) short Pt[4 * 32 * PTS];
    __shared__ float gs[2][64];

    const int tid  = threadIdx.x;
    const int wave = tid >> 6;
    const int lane = tid & 63;
    const int li   = lane & 15;
    const int quad = lane >> 4;

    const int bx = blockIdx.x;          // b*512 + h*64 + qt*4 + ks
    const int ks = bx & 3;
    const int qt = (bx >> 2) & 15;
    const int h  = (bx >> 6) & 7;
    const int b  = bx >> 9;
    const size_t bh = (size_t)(b * 8 + h);

    // Q fragments: 2 m-subtiles x 2 k-halves
    const bf16* qb0 = qp + (bh * 2048 + (size_t)qt * 128 + wave * 32 + li) * 64;
    bf16x8 aq[2][2];
    aq[0][0] = load8(qb0 + quad * 8);
    aq[0][1] = load8(qb0 + 32 + quad * 8);
    aq[1][0] = load8(qb0 + 16 * 64 + quad * 8);
    aq[1][1] = load8(qb0 + 16 * 64 + 32 + quad * 8);

    f32x4 zero = {0.f, 0.f, 0.f, 0.f};
    f32x4 o[2][4];
    for (int mt = 0; mt < 2; ++mt)
        for (int t = 0; t < 4; ++t) o[mt][t] = zero;
    float lsum[2][4] = {{0.f, 0.f, 0.f, 0.f}, {0.f, 0.f, 0.f, 0.f}};

    const bf16* ksrc  = kp  + bh * 4096 * 64;
    const bf16* vsrc  = vpt + bh * 64 * 4096;
    const float* gsrc = g2 + (size_t)b * 4096;

    short* PtW = &Pt[wave * 32 * PTS];

    // DMA source pattern (per lane, same every chunk)
    const int rDMA = lane >> 3;                    // row within 8-row half
    const int cDMA = ((lane & 7) ^ rDMA) << 3;     // swizzled col (bf16 units)
    const int rA = wave * 16 + rDMA;               // half 0 row
    const int rB = rA + 8;                         // half 1 row

    // issue DMA for tile kt into buffer buf (wave-uniform LDS bases)
    auto issue = [&](int kt, int buf) {
        const bf16* kst = ksrc + (size_t)kt * 4096;
        const bf16* vst = vsrc + kt * 64;
        async16(kst + rA * 64 + cDMA, &Kt[buf][wave * 1024]);
        async16(kst + rB * 64 + cDMA, &Kt[buf][wave * 1024 + 512]);
        async16(vst + (size_t)rA * 4096 + cDMA, &Vt[buf][wave * 1024]);
        async16(vst + (size_t)rB * 4096 + cDMA, &Vt[buf][wave * 1024 + 512]);
        if (wave == 0) async4(gsrc + kt * 64 + lane, &gs[buf][0]);
    };

    issue(ks * 16, 0);

    for (int i = 0; i < 16; ++i) {
        const int cur = i & 1;
        __syncthreads();                 // drains vmcnt: tile i ready in cur
        if (i < 15) issue(ks * 16 + i + 1, cur ^ 1);   // overlaps compute

        // S (32 x 64) = Q @ K_tile^T, then P = exp2(S*SCALE_LOG2E + g2)
        for (int t = 0; t < 4; ++t) {
            const int R   = t * 16 + li;
            const int rsw = R & 7;
            bf16x8 bk0 = load8(&Kt[cur][R * 64 + ((quad ^ rsw) << 3)]);
            bf16x8 bk1 = load8(&Kt[cur][R * 64 + (((4 + quad) ^ rsw) << 3)]);
            const float gv = gs[cur][R];
            for (int mt = 0; mt < 2; ++mt) {
                f32x4 acc = zero;
                acc = MFMA16(aq[mt][0], bk0, acc);
                acc = MFMA16(aq[mt][1], bk1, acc);
                for (int r = 0; r < 4; ++r) {
                    const float p = __builtin_amdgcn_exp2f(fmaf(acc[r], SCALE_LOG2E, gv));
                    lsum[mt][r] += p;
                    PtW[(mt * 16 + quad * 4 + r) * PTS + t * 16 + li] = f2bf_fast(p);
                }
            }
        }

        // O += P @ V_tile
        bf16x8 ap[2][2];
        ap[0][0] = *reinterpret_cast<bf16x8*>(&PtW[li * PTS + quad * 8]);
        ap[0][1] = *reinterpret_cast<bf16x8*>(&PtW[li * PTS + 32 + quad * 8]);
        ap[1][0] = *reinterpret_cast<bf16x8*>(&PtW[(16 + li) * PTS + quad * 8]);
        ap[1][1] = *reinterpret_cast<bf16x8*>(&PtW[(16 + li) * PTS + 32 + quad * 8]);
        for (int t = 0; t < 4; ++t) {
            const int R   = t * 16 + li;
            const int rsw = R & 7;
            bf16x8 bv0 = load8(&Vt[cur][R * 64 + ((quad ^ rsw) << 3)]);
            bf16x8 bv1 = load8(&Vt[cur][R * 64 + (((4 + quad) ^ rsw) << 3)]);
            for (int mt = 0; mt < 2; ++mt) {
                o[mt][t] = MFMA16(ap[mt][0], bv0, o[mt][t]);
                o[mt][t] = MFMA16(ap[mt][1], bv1, o[mt][t]);
            }
        }
        // no bottom barrier: next iteration's top barrier orders buffer reuse
    }

    // reduce l across the 16 lanes of each row group
    for (int off = 1; off < 16; off <<= 1)
        for (int mt = 0; mt < 2; ++mt)
            for (int r = 0; r < 4; ++r)
                lsum[mt][r] += __shfl_xor(lsum[mt][r], off);

    // write bf16 partial O (unnormalized) + fp32 l
    bf16* ob = Opart + ((size_t)bx * 128 + wave * 32) * 64;
    for (int mt = 0; mt < 2; ++mt)
        for (int t = 0; t < 4; ++t)
            for (int r = 0; r < 4; ++r)
                ob[(size_t)(mt * 16 + quad * 4 + r) * 64 + t * 16 + li] =
                    __float2bfloat16(o[mt][t][r]);
    if (li == 0)
        for (int mt = 0; mt < 2; ++mt)
            for (int r = 0; r < 4; ++r)
                lpart[(size_t)bx * 128 + wave * 32 + mt * 16 + quad * 4 + r] = lsum[mt][r];
}

// ---------------------------------------------------------------------------
// Combine 4 K-split partials (plain sums). Grid 512 x 256 thr.
// ---------------------------------------------------------------------------
__global__ void attn_combine(const bf16* __restrict__ Opart,
                             const float* __restrict__ lpart,
                             bf16* __restrict__ op) {
    const int gidx = blockIdx.x * 256 + threadIdx.x;  // 0..131071
    const int row  = gidx >> 2;                        // 0..32767 = (b,h,q)
    const int c0   = (gidx & 3) * 16;
    const int b    = row >> 14;
    const int h    = (row >> 11) & 7;
    const int q    = row & 2047;
    const int qt   = q >> 7;
    const int r128 = q & 127;
    const int base = (((b * 8 + h) * 16) + qt) * 4;

    float acc[16];
    for (int j = 0; j < 16; ++j) acc[j] = 0.f;
    float L = 0.f;
    for (int s = 0; s < 4; ++s) {
        const bf16* src = Opart + ((size_t)(base + s) * 128 + r128) * 64 + c0;
        bf16x8 v0 = load8(src);
        bf16x8 v1 = load8(src + 8);
        for (int j = 0; j < 8; ++j) {
            acc[j]     += bfb2f(v0[j]);
            acc[8 + j] += bfb2f(v1[j]);
        }
        L += lpart[(size_t)(base + s) * 128 + r128];
    }
    const float invL = 1.0f / L;

    bf16* dst = op + ((size_t)b * 2048 + q) * 512 + h * 64 + c0;
    bf16x8 o0, o1;
    for (int j = 0; j < 8; ++j) {
        o0[j] = f2bf(acc[j] * invL);
        o1[j] = f2bf(acc[8 + j] * invL);
    }
    *reinterpret_cast<bf16x8*>(dst)     = o0;
    *reinterpret_cast<bf16x8*>(dst + 8) = o1;
}

// ---------------------------------------------------------------------------
extern "C" void kernel_launch(void* const* d_in, const int* in_sizes, int n_in,
                              void* d_out, int out_size, void* d_ws, size_t ws_size,
                              hipStream_t stream) {
    const float* q    = (const float*)d_in[0];
    const float* kv   = (const float*)d_in[1];
    const float* gate = (const float*)d_in[2];
    const int*   mask = (const int*)d_in[3];
    const float* Wq = (const float*)d_in[4];  const float* bq = (const float*)d_in[5];
    const float* Wk = (const float*)d_in[6];  const float* bk = (const float*)d_in[7];
    const float* Wv = (const float*)d_in[8];  const float* bv = (const float*)d_in[9];
    const float* Wo = (const float*)d_in[10]; const float* bo = (const float*)d_in[11];
    float* out = (float*)d_out;

    // workspace (MB offsets): g2@0, Wqb@1, Wkb@1.5, Wvb@2, Wob@2.5, qb@3(4),
    // kvb@7(8), qp@15(4), kp@19(8), vpt@27(8), op@35(4),
    // Opart bf16 @39(16), lpart fp32 @55(0.5)  -> ~56 MB
    char* ws = (char*)d_ws;
    float* g2  = (float*)ws;
    bf16* Wqb  = (bf16*)(ws + (1u  << 20));
    bf16* Wkb  = (bf16*)(ws + (1u  << 20) + (512u << 10));
    bf16* Wvb  = (bf16*)(ws + (2u  << 20));
    bf16* Wob  = (bf16*)(ws + (2u  << 20) + (512u << 10));
    bf16* qb   = (bf16*)(ws + (3u  << 20));
    bf16* kvb  = (bf16*)(ws + (7u  << 20));
    bf16* qp   = (bf16*)(ws + (15u << 20));
    bf16* kp   = (bf16*)(ws + (19u << 20));
    bf16* vpt  = (bf16*)(ws + (27u << 20));
    bf16* op   = (bf16*)(ws + (35u << 20));
    bf16* Opart = (bf16*)(ws + (39u << 20));
    float* lpart = (float*)(ws + (55u << 20));

    prep_all<<<7200, 256, 0, stream>>>(q, kv, Wq, Wk, Wv, Wo, gate, mask,
                                       qb, kvb, Wqb, Wkb, Wvb, Wob, g2);
    proj_qkv<<<dim3(8, 160), 256, 0, stream>>>(qb, kvb, Wqb, bq, Wkb, bk,
                                               Wvb, bv, qp, kp, vpt);
    attn_kernel<<<1024, 256, 0, stream>>>(qp, kp, vpt, g2, Opart, lpart);
    attn_combine<<<512, 256, 0, stream>>>(Opart, lpart, op);
    proj_o<<<dim3(8, 32), 256, 0, stream>>>(op, Wob, bo, out);
}